// Round 1
// baseline (602.320 us; speedup 1.0000x reference)
//
#include <hip/hip_runtime.h>

#define M_DIM 8192
#define N_DIM 4096
#define K_DIM 4096

typedef __attribute__((ext_vector_type(8))) __bf16 bf16x8;
typedef __attribute__((ext_vector_type(4))) __bf16 bf16x4;
typedef __attribute__((ext_vector_type(4))) float floatx4;

// ---------- async global->LDS, 16B per lane (wave-uniform LDS base) ----------
__device__ __forceinline__ void async_copy16(const void* g, void* l) {
    __builtin_amdgcn_global_load_lds(
        (const __attribute__((address_space(1))) void*)g,
        (__attribute__((address_space(3))) void*)l,
        16, 0, 0);
}

// raw barrier without compiler vmcnt(0) drain; memory clobbers stop IR reordering
__device__ __forceinline__ void block_sync() {
    asm volatile("" ::: "memory");
    __builtin_amdgcn_s_barrier();
    asm volatile("" ::: "memory");
}

// ---------- deterministic reductions (fp64) ----------
__device__ __forceinline__ double wave_reduce_d(double v) {
    #pragma unroll
    for (int o = 32; o > 0; o >>= 1) v += __shfl_down(v, o, 64);
    return v;
}
__device__ __forceinline__ unsigned wave_reduce_u(unsigned v) {
    #pragma unroll
    for (int o = 32; o > 0; o >>= 1) v += __shfl_down(v, o, 64);
    return v;
}

// K1 (fused): blocks [0,2048) -> partial sums of |W|; blocks [2048,10240) -> x fp32->bf16
__global__ __launch_bounds__(256) void k_pre(const float4* __restrict__ w4,
                                             double* __restrict__ part,
                                             const float4* __restrict__ x4,
                                             bf16x4* __restrict__ xb) {
    const int tid = threadIdx.x;
    if (blockIdx.x < 2048) {
        int idx = blockIdx.x * 256 + tid;
        double s = 0.0;
        #pragma unroll
        for (int it = 0; it < 8; ++it) {
            float4 v = w4[idx + it * (2048 * 256)];
            s += (double)fabsf(v.x) + (double)fabsf(v.y) +
                 (double)fabsf(v.z) + (double)fabsf(v.w);
        }
        s = wave_reduce_d(s);
        __shared__ double sm[4];
        if ((tid & 63) == 0) sm[tid >> 6] = s;
        __syncthreads();
        if (tid == 0) part[blockIdx.x] = sm[0] + sm[1] + sm[2] + sm[3];
    } else {
        int idx = (blockIdx.x - 2048) * 256 + tid;
        #pragma unroll
        for (int it = 0; it < 4; ++it) {
            int i = idx + it * (8192 * 256);
            float4 v = x4[i];
            bf16x4 o;
            o[0] = (__bf16)v.x; o[1] = (__bf16)v.y;
            o[2] = (__bf16)v.z; o[3] = (__bf16)v.w;
            xb[i] = o;
        }
    }
}

// K2: block-redundant delta from part[2048]; quantize; masked partial sums.
// Per-element math BIT-IDENTICAL to the passing kernel (f64 delta/compare).
__global__ __launch_bounds__(256) void k_quant(const float4* __restrict__ w4,
                                               bf16x4* __restrict__ tern,
                                               const double* __restrict__ part,
                                               double* __restrict__ scal,
                                               double* __restrict__ pm,
                                               unsigned* __restrict__ pc) {
    const int tid = threadIdx.x;
    double s = 0.0;
    #pragma unroll
    for (int i = 0; i < 8; ++i) s += part[tid + i * 256];
    s = wave_reduce_d(s);
    __shared__ double sm[4];
    if ((tid & 63) == 0) sm[tid >> 6] = s;
    __syncthreads();
    const double mean = (sm[0] + sm[1] + sm[2] + sm[3]) * (1.0 / 16777216.0);
    const double delta = 0.7 * mean;
    if (blockIdx.x == 0 && tid == 0) scal[0] = mean;

    int idx = blockIdx.x * 256 + tid;
    double msum = 0.0;
    unsigned cnt = 0;
    #pragma unroll
    for (int it = 0; it < 8; ++it) {
        int i = idx + it * (2048 * 256);
        float4 v = w4[i];
        float e[4] = {v.x, v.y, v.z, v.w};
        bf16x4 o;
        #pragma unroll
        for (int c = 0; c < 4; ++c) {
            float wv = e[c];
            float t = ((double)wv > delta) ? 1.0f
                    : (((double)wv < -delta) ? -1.0f : 0.0f);
            if (t != 0.0f) { msum += (double)fabsf(wv); cnt++; }
            o[c] = (__bf16)t;
        }
        tern[i] = o;
    }
    msum = wave_reduce_d(msum);
    cnt  = wave_reduce_u(cnt);
    __shared__ double smd[4];
    __shared__ unsigned smu[4];
    if ((tid & 63) == 0) { smd[tid >> 6] = msum; smu[tid >> 6] = cnt; }
    __syncthreads();
    if (tid == 0) {
        pm[blockIdx.x] = smd[0] + smd[1] + smd[2] + smd[3];
        pc[blockIdx.x] = smu[0] + smu[1] + smu[2] + smu[3];
    }
}

// ---------- GEMM: C[m][n] = alpha * sum_k A[m][k]*B[n][k] + bias[n] ----------
// 256x256 tile, 8 waves (2Mx4N, per-wave 128x64), BK=32, 4-deep LDS ring.
// Counted vmcnt(8) (never 0 in main loop), raw s_barrier, setprio around MFMA.
// LDS chunk layout + XOR swizzle identical to prior kernel (measured 0 conflicts):
// chunk = 16 rows x 32 cols; pos (lane&3) holds global octet (lane&3)^((srow>>1)&3).
__global__ __launch_bounds__(512, 2) void ternary_gemm(
    const __bf16* __restrict__ A,    // M x K (x in bf16)
    const __bf16* __restrict__ B,    // N x K (ternary in bf16)
    const float*  __restrict__ bias, // N
    const double* __restrict__ scal, // [0] = mean|w| fallback
    const double* __restrict__ pm,   // 2048 masked partial sums
    const unsigned* __restrict__ pc, // 2048 masked partial counts
    float* __restrict__ C)           // M x N
{
    __shared__ __attribute__((aligned(128))) __bf16 As[4][8192];  // 64 KB
    __shared__ __attribute__((aligned(128))) __bf16 Bs[4][8192];  // 64 KB
    __shared__ double smd[8];
    __shared__ unsigned smu[8];

    const int tid  = threadIdx.x;
    const int w    = tid >> 6;
    const int lane = tid & 63;
    const int quad = lane >> 4;
    const int l16  = lane & 15;
    const int wr = w >> 2;   // 0..1 -> rows wr*128
    const int wc = w & 3;    // 0..3 -> cols wc*64

    // bijective XCD swizzle (512 % 8 == 0): chunk of 64 consecutive ids per XCD
    const int id = (blockIdx.x & 7) * 64 + (blockIdx.x >> 3);
    const int br = id >> 4;  // 0..31 M tile
    const int bc = id & 15;  // 0..15 N tile

    // staging geometry: wave w stages chunks {w, w+8} of A and of B each K-tile
    const int srow = lane >> 2;
    const int scol = ((lane & 3) ^ ((srow >> 1) & 3)) * 8;  // pre-swizzled source

    const __bf16* gA0 = A + (size_t)(br * 256 + w * 16 + srow) * K_DIM + scol;
    const __bf16* gA1 = gA0 + (size_t)128 * K_DIM;
    const __bf16* gB0 = B + (size_t)(bc * 256 + w * 16 + srow) * K_DIM + scol;
    const __bf16* gB1 = gB0 + (size_t)128 * K_DIM;

    floatx4 acc[8][4] = {};

    // fragment read: octet for (quad, row l16) sits at position quad^((l16>>1)&3)
    const int swz   = (quad ^ ((l16 >> 1) & 3)) * 8;
    const int a_off = (wr * 128 + l16) * 32 + swz;
    const int b_off = (wc * 64 + l16) * 32 + swz;

#define STAGE_A(ktt) do {                                        \
        const int _sb = (ktt) & 3; const int _so = (ktt) * 32;   \
        async_copy16(gA0 + _so, &As[_sb][w * 512]);              \
        async_copy16(gA1 + _so, &As[_sb][(w + 8) * 512]);        \
    } while (0)
#define STAGE_B(ktt) do {                                        \
        const int _sb = (ktt) & 3; const int _so = (ktt) * 32;   \
        async_copy16(gB0 + _so, &Bs[_sb][w * 512]);              \
        async_copy16(gB1 + _so, &Bs[_sb][(w + 8) * 512]);        \
    } while (0)

    // prologue: stage tiles 0,1,2 (12 loads per wave in flight)
    STAGE_A(0); STAGE_B(0);
    STAGE_A(1); STAGE_B(1);
    STAGE_A(2); STAGE_B(2);

#define TILE(kt_, VMN, DO_STAGE_) do {                                         \
        asm volatile("s_waitcnt vmcnt(" #VMN ")" ::: "memory");                \
        block_sync();                                                          \
        const int _buf = (kt_) & 3;                                            \
        const __bf16* _Ab = As[_buf];                                          \
        const __bf16* _Bb = Bs[_buf];                                          \
        bf16x8 _a[4], _b[4];                                                   \
        _Pragma("unroll")                                                      \
        for (int i = 0; i < 4; ++i)                                            \
            _a[i] = *(const bf16x8*)(_Ab + a_off + i * 512);                   \
        _Pragma("unroll")                                                      \
        for (int j = 0; j < 4; ++j)                                            \
            _b[j] = *(const bf16x8*)(_Bb + b_off + j * 512);                   \
        if (DO_STAGE_) STAGE_A((kt_) + 3);                                     \
        block_sync();                                                          \
        __builtin_amdgcn_sched_barrier(0);                                     \
        __builtin_amdgcn_s_setprio(1);                                         \
        _Pragma("unroll")                                                      \
        for (int i = 0; i < 4; ++i)                                            \
            _Pragma("unroll")                                                  \
            for (int j = 0; j < 4; ++j)                                        \
                acc[i][j] = __builtin_amdgcn_mfma_f32_16x16x32_bf16(           \
                    _a[i], _b[j], acc[i][j], 0, 0, 0);                         \
        __builtin_amdgcn_s_setprio(0);                                         \
        __builtin_amdgcn_sched_barrier(0);                                     \
        block_sync();                                                          \
        _Pragma("unroll")                                                      \
        for (int i = 0; i < 4; ++i)                                            \
            _a[i] = *(const bf16x8*)(_Ab + a_off + (4 + i) * 512);             \
        if (DO_STAGE_) STAGE_B((kt_) + 3);                                     \
        block_sync();                                                          \
        __builtin_amdgcn_sched_barrier(0);                                     \
        __builtin_amdgcn_s_setprio(1);                                         \
        _Pragma("unroll")                                                      \
        for (int i = 0; i < 4; ++i)                                            \
            _Pragma("unroll")                                                  \
            for (int j = 0; j < 4; ++j)                                        \
                acc[4 + i][j] = __builtin_amdgcn_mfma_f32_16x16x32_bf16(       \
                    _a[i], _b[j], acc[4 + i][j], 0, 0, 0);                     \
        __builtin_amdgcn_s_setprio(0);                                         \
        __builtin_amdgcn_sched_barrier(0);                                     \
    } while (0)

    // main loop: 128 K-tiles; stage kt+3 while computing kt; vmcnt never 0
    for (int kt = 0; kt < 125; ++kt) TILE(kt, 8, true);
    TILE(125, 8, false);   // outstanding 12 -> wait tile 125
    TILE(126, 4, false);   // outstanding  8 -> wait tile 126
    TILE(127, 0, false);   // outstanding  4 -> drain

#undef TILE
#undef STAGE_A
#undef STAGE_B

    // block-redundant alpha reduce (deterministic, identical in every block)
    double s = 0.0; unsigned c = 0;
    #pragma unroll
    for (int i = 0; i < 4; ++i) { s += pm[tid + i * 512]; c += pc[tid + i * 512]; }
    s = wave_reduce_d(s);
    c = wave_reduce_u(c);
    if (lane == 0) { smd[w] = s; smu[w] = c; }
    __syncthreads();
    double ms = 0.0; unsigned ct = 0;
    #pragma unroll
    for (int i = 0; i < 8; ++i) { ms += smd[i]; ct += smu[i]; }
    const float alpha = (float)(ct > 0 ? ms / (double)ct : scal[0]);

    float bv[4];
    #pragma unroll
    for (int j = 0; j < 4; ++j)
        bv[j] = bias[bc * 256 + wc * 64 + j * 16 + l16];

    // C/D layout (16x16x32): col = lane&15, row = quad*4 + reg
    #pragma unroll
    for (int i = 0; i < 8; ++i) {
        const int row0 = br * 256 + wr * 128 + i * 16 + quad * 4;
        #pragma unroll
        for (int j = 0; j < 4; ++j) {
            const int col = bc * 256 + wc * 64 + j * 16 + l16;
            #pragma unroll
            for (int r = 0; r < 4; ++r)
                C[(size_t)(row0 + r) * N_DIM + col] = acc[i][j][r] * alpha + bv[j];
        }
    }
}

extern "C" void kernel_launch(void* const* d_in, const int* in_sizes, int n_in,
                              void* d_out, int out_size, void* d_ws, size_t ws_size,
                              hipStream_t stream) {
    const float* x    = (const float*)d_in[0];  // (8192, 4096) fp32
    const float* w    = (const float*)d_in[1];  // (4096, 4096) fp32
    const float* bias = (const float*)d_in[2];  // (4096,) fp32
    float* out = (float*)d_out;                 // (8192, 4096) fp32

    char* ws = (char*)d_ws;
    double*   d_scal = (double*)ws;               // [0] = mean|w|
    double*   part   = (double*)(ws + 64);        // 2048 doubles
    double*   pm     = (double*)(ws + 16448);     // 2048 doubles
    unsigned* pc     = (unsigned*)(ws + 32832);   // 2048 uints
    __bf16*   xb     = (__bf16*)(ws + 65536);                                   // 64 MB
    __bf16*   tern   = (__bf16*)(ws + 65536 + (size_t)M_DIM * K_DIM * 2);       // 32 MB

    k_pre<<<10240, 256, 0, stream>>>((const float4*)w, part, (const float4*)x, (bf16x4*)xb);
    k_quant<<<2048, 256, 0, stream>>>((const float4*)w, (bf16x4*)tern, part, d_scal, pm, pc);

    ternary_gemm<<<512, 512, 0, stream>>>(xb, tern, bias, d_scal, pm, pc, out);
}

// Round 2
// 516.268 us; speedup vs baseline: 1.1667x; 1.1667x over previous
//
#include <hip/hip_runtime.h>

#define M_DIM 8192
#define N_DIM 4096
#define K_DIM 4096

typedef __attribute__((ext_vector_type(8))) __bf16 bf16x8;
typedef __attribute__((ext_vector_type(4))) __bf16 bf16x4;
typedef __attribute__((ext_vector_type(4))) float floatx4;

// ---------- async global->LDS, 16B per lane (wave-uniform LDS base) ----------
__device__ __forceinline__ void async_copy16(const void* g, void* l) {
    __builtin_amdgcn_global_load_lds(
        (const __attribute__((address_space(1))) void*)g,
        (__attribute__((address_space(3))) void*)l,
        16, 0, 0);
}

// 32-bit LDS byte address for inline-asm ds_read (compiler-invisible LDS read)
__device__ __forceinline__ unsigned lds_addr(const void* p) {
    return (unsigned)(unsigned long long)(const __attribute__((address_space(3))) void*)p;
}
__device__ __forceinline__ bf16x8 lds_read_b128(unsigned addr) {
    bf16x8 r;
    asm volatile("ds_read_b128 %0, %1" : "=v"(r) : "v"(addr));
    return r;
}

// ---------- deterministic reductions (fp64) ----------
__device__ __forceinline__ double wave_reduce_d(double v) {
    #pragma unroll
    for (int o = 32; o > 0; o >>= 1) v += __shfl_down(v, o, 64);
    return v;
}
__device__ __forceinline__ unsigned wave_reduce_u(unsigned v) {
    #pragma unroll
    for (int o = 32; o > 0; o >>= 1) v += __shfl_down(v, o, 64);
    return v;
}

// K1 (fused): blocks [0,2048) -> partial sums of |W|; blocks [2048,10240) -> x fp32->bf16
__global__ __launch_bounds__(256) void k_pre(const float4* __restrict__ w4,
                                             double* __restrict__ part,
                                             const float4* __restrict__ x4,
                                             bf16x4* __restrict__ xb) {
    const int tid = threadIdx.x;
    if (blockIdx.x < 2048) {
        int idx = blockIdx.x * 256 + tid;
        double s = 0.0;
        #pragma unroll
        for (int it = 0; it < 8; ++it) {
            float4 v = w4[idx + it * (2048 * 256)];
            s += (double)fabsf(v.x) + (double)fabsf(v.y) +
                 (double)fabsf(v.z) + (double)fabsf(v.w);
        }
        s = wave_reduce_d(s);
        __shared__ double sm[4];
        if ((tid & 63) == 0) sm[tid >> 6] = s;
        __syncthreads();
        if (tid == 0) part[blockIdx.x] = sm[0] + sm[1] + sm[2] + sm[3];
    } else {
        int idx = (blockIdx.x - 2048) * 256 + tid;
        #pragma unroll
        for (int it = 0; it < 4; ++it) {
            int i = idx + it * (8192 * 256);
            float4 v = x4[i];
            bf16x4 o;
            o[0] = (__bf16)v.x; o[1] = (__bf16)v.y;
            o[2] = (__bf16)v.z; o[3] = (__bf16)v.w;
            xb[i] = o;
        }
    }
}

// K2: block-redundant delta from part[2048]; quantize; masked partial sums.
// Per-element math BIT-IDENTICAL to the passing kernel (f64 delta/compare).
__global__ __launch_bounds__(256) void k_quant(const float4* __restrict__ w4,
                                               bf16x4* __restrict__ tern,
                                               const double* __restrict__ part,
                                               double* __restrict__ scal,
                                               double* __restrict__ pm,
                                               unsigned* __restrict__ pc) {
    const int tid = threadIdx.x;
    double s = 0.0;
    #pragma unroll
    for (int i = 0; i < 8; ++i) s += part[tid + i * 256];
    s = wave_reduce_d(s);
    __shared__ double sm[4];
    if ((tid & 63) == 0) sm[tid >> 6] = s;
    __syncthreads();
    const double mean = (sm[0] + sm[1] + sm[2] + sm[3]) * (1.0 / 16777216.0);
    const double delta = 0.7 * mean;
    if (blockIdx.x == 0 && tid == 0) scal[0] = mean;

    int idx = blockIdx.x * 256 + tid;
    double msum = 0.0;
    unsigned cnt = 0;
    #pragma unroll
    for (int it = 0; it < 8; ++it) {
        int i = idx + it * (2048 * 256);
        float4 v = w4[i];
        float e[4] = {v.x, v.y, v.z, v.w};
        bf16x4 o;
        #pragma unroll
        for (int c = 0; c < 4; ++c) {
            float wv = e[c];
            float t = ((double)wv > delta) ? 1.0f
                    : (((double)wv < -delta) ? -1.0f : 0.0f);
            if (t != 0.0f) { msum += (double)fabsf(wv); cnt++; }
            o[c] = (__bf16)t;
        }
        tern[i] = o;
    }
    msum = wave_reduce_d(msum);
    cnt  = wave_reduce_u(cnt);
    __shared__ double smd[4];
    __shared__ unsigned smu[4];
    if ((tid & 63) == 0) { smd[tid >> 6] = msum; smu[tid >> 6] = cnt; }
    __syncthreads();
    if (tid == 0) {
        pm[blockIdx.x] = smd[0] + smd[1] + smd[2] + smd[3];
        pc[blockIdx.x] = smu[0] + smu[1] + smu[2] + smu[3];
    }
}

// ---------- GEMM: C[m][n] = alpha * sum_k A[m][k]*B[n][k] + bias[n] ----------
// 256x256 tile, 8 waves (2Mx4N, per-wave 128x64), BK=32, 4-deep LDS ring.
// T3+T4: ONE vmcnt(8)+raw-barrier per K-tile (never 0 in main loop); fragment
// reads are inline-asm ds_read_b128 (invisible to compiler's waitcnt pass, so
// no conservative vmcnt(0) drain); counted lgkmcnt(4)/lgkmcnt(0) + rule-#18
// sched_barrier(0) before each MFMA cluster; T5 setprio around MFMA.
// LDS chunk layout + XOR swizzle identical to round-0 (measured 0 conflicts).
__global__ __launch_bounds__(512, 2) void ternary_gemm(
    const __bf16* __restrict__ A,    // M x K (x in bf16)
    const __bf16* __restrict__ B,    // N x K (ternary in bf16)
    const float*  __restrict__ bias, // N
    const double* __restrict__ scal, // [0] = mean|w| fallback
    const double* __restrict__ pm,   // 2048 masked partial sums
    const unsigned* __restrict__ pc, // 2048 masked partial counts
    float* __restrict__ C)           // M x N
{
    __shared__ __attribute__((aligned(128))) __bf16 As[4][8192];  // 64 KB
    __shared__ __attribute__((aligned(128))) __bf16 Bs[4][8192];  // 64 KB
    __shared__ double smd[8];
    __shared__ unsigned smu[8];

    const int tid  = threadIdx.x;
    const int w    = tid >> 6;
    const int lane = tid & 63;
    const int quad = lane >> 4;
    const int l16  = lane & 15;
    const int wr = w >> 2;   // 0..1 -> rows wr*128
    const int wc = w & 3;    // 0..3 -> cols wc*64

    // bijective XCD swizzle (512 % 8 == 0): chunk of 64 consecutive ids per XCD
    const int id = (blockIdx.x & 7) * 64 + (blockIdx.x >> 3);
    const int br = id >> 4;  // 0..31 M tile
    const int bc = id & 15;  // 0..15 N tile

    // staging geometry: wave w stages chunks {w, w+8} of A and of B each K-tile
    const int srow = lane >> 2;
    const int scol = ((lane & 3) ^ ((srow >> 1) & 3)) * 8;  // pre-swizzled source

    const __bf16* gA0 = A + (size_t)(br * 256 + w * 16 + srow) * K_DIM + scol;
    const __bf16* gA1 = gA0 + (size_t)128 * K_DIM;
    const __bf16* gB0 = B + (size_t)(bc * 256 + w * 16 + srow) * K_DIM + scol;
    const __bf16* gB1 = gB0 + (size_t)128 * K_DIM;

    floatx4 acc[8][4] = {};

    // fragment read: octet for (quad, row l16) sits at position quad^((l16>>1)&3)
    const int swz   = (quad ^ ((l16 >> 1) & 3)) * 8;
    const int a_off = (wr * 128 + l16) * 32 + swz;
    const int b_off = (wc * 64 + l16) * 32 + swz;

    const unsigned aAddr0 = lds_addr(&As[0][0]) + (unsigned)(a_off * 2);
    const unsigned bAddr0 = lds_addr(&Bs[0][0]) + (unsigned)(b_off * 2);

#define STAGE_A(ktt) do {                                        \
        const int _sb = (ktt) & 3; const int _so = (ktt) * 32;   \
        async_copy16(gA0 + _so, &As[_sb][w * 512]);              \
        async_copy16(gA1 + _so, &As[_sb][(w + 8) * 512]);        \
    } while (0)
#define STAGE_B(ktt) do {                                        \
        const int _sb = (ktt) & 3; const int _so = (ktt) * 32;   \
        async_copy16(gB0 + _so, &Bs[_sb][w * 512]);              \
        async_copy16(gB1 + _so, &Bs[_sb][(w + 8) * 512]);        \
    } while (0)

    // prologue: stage tiles 0,1,2 (12 loads per wave in flight)
    STAGE_A(0); STAGE_B(0);
    STAGE_A(1); STAGE_B(1);
    STAGE_A(2); STAGE_B(2);

#define TILE(kt_, VMN, DO_STAGE_) do {                                         \
        asm volatile("s_waitcnt vmcnt(" #VMN ")" ::: "memory");                \
        __builtin_amdgcn_s_barrier();                                          \
        const unsigned _bufB = (unsigned)(((kt_) & 3) * 16384);                \
        bf16x8 _a[8], _b[4];                                                   \
        _Pragma("unroll")                                                      \
        for (int i = 0; i < 4; ++i)                                            \
            _a[i] = lds_read_b128(aAddr0 + _bufB + (unsigned)(i * 1024));      \
        _Pragma("unroll")                                                      \
        for (int j = 0; j < 4; ++j)                                            \
            _b[j] = lds_read_b128(bAddr0 + _bufB + (unsigned)(j * 1024));      \
        _Pragma("unroll")                                                      \
        for (int i = 4; i < 8; ++i)                                            \
            _a[i] = lds_read_b128(aAddr0 + _bufB + (unsigned)(i * 1024));      \
        if (DO_STAGE_) { STAGE_A((kt_) + 3); STAGE_B((kt_) + 3); }             \
        asm volatile("s_waitcnt lgkmcnt(4)" ::: "memory");                     \
        __builtin_amdgcn_sched_barrier(0);                                     \
        __builtin_amdgcn_s_setprio(1);                                         \
        _Pragma("unroll")                                                      \
        for (int i = 0; i < 4; ++i)                                            \
            _Pragma("unroll")                                                  \
            for (int j = 0; j < 4; ++j)                                        \
                acc[i][j] = __builtin_amdgcn_mfma_f32_16x16x32_bf16(           \
                    _a[i], _b[j], acc[i][j], 0, 0, 0);                         \
        __builtin_amdgcn_s_setprio(0);                                         \
        asm volatile("s_waitcnt lgkmcnt(0)" ::: "memory");                     \
        __builtin_amdgcn_sched_barrier(0);                                     \
        __builtin_amdgcn_s_setprio(1);                                         \
        _Pragma("unroll")                                                      \
        for (int i = 0; i < 4; ++i)                                            \
            _Pragma("unroll")                                                  \
            for (int j = 0; j < 4; ++j)                                        \
                acc[4 + i][j] = __builtin_amdgcn_mfma_f32_16x16x32_bf16(       \
                    _a[4 + i], _b[j], acc[4 + i][j], 0, 0, 0);                 \
        __builtin_amdgcn_s_setprio(0);                                         \
        __builtin_amdgcn_sched_barrier(0);                                     \
    } while (0)

    // main loop: 128 K-tiles; stage kt+3 while computing kt; vmcnt never 0
    for (int kt = 0; kt < 125; ++kt) TILE(kt, 8, true);
    TILE(125, 8, false);   // outstanding 12 -> wait tile 125
    TILE(126, 4, false);   // outstanding  8 -> wait tile 126
    TILE(127, 0, false);   // outstanding  4 -> drain

#undef TILE
#undef STAGE_A
#undef STAGE_B

    // block-redundant alpha reduce (deterministic, identical in every block)
    double s = 0.0; unsigned c = 0;
    #pragma unroll
    for (int i = 0; i < 4; ++i) { s += pm[tid + i * 512]; c += pc[tid + i * 512]; }
    s = wave_reduce_d(s);
    c = wave_reduce_u(c);
    if (lane == 0) { smd[w] = s; smu[w] = c; }
    __syncthreads();
    double ms = 0.0; unsigned ct = 0;
    #pragma unroll
    for (int i = 0; i < 8; ++i) { ms += smd[i]; ct += smu[i]; }
    const float alpha = (float)(ct > 0 ? ms / (double)ct : scal[0]);

    float bv[4];
    #pragma unroll
    for (int j = 0; j < 4; ++j)
        bv[j] = bias[bc * 256 + wc * 64 + j * 16 + l16];

    // C/D layout (16x16x32): col = lane&15, row = quad*4 + reg
    #pragma unroll
    for (int i = 0; i < 8; ++i) {
        const int row0 = br * 256 + wr * 128 + i * 16 + quad * 4;
        #pragma unroll
        for (int j = 0; j < 4; ++j) {
            const int col = bc * 256 + wc * 64 + j * 16 + l16;
            #pragma unroll
            for (int r = 0; r < 4; ++r)
                C[(size_t)(row0 + r) * N_DIM + col] = acc[i][j][r] * alpha + bv[j];
        }
    }
}

extern "C" void kernel_launch(void* const* d_in, const int* in_sizes, int n_in,
                              void* d_out, int out_size, void* d_ws, size_t ws_size,
                              hipStream_t stream) {
    const float* x    = (const float*)d_in[0];  // (8192, 4096) fp32
    const float* w    = (const float*)d_in[1];  // (4096, 4096) fp32
    const float* bias = (const float*)d_in[2];  // (4096,) fp32
    float* out = (float*)d_out;                 // (8192, 4096) fp32

    char* ws = (char*)d_ws;
    double*   d_scal = (double*)ws;               // [0] = mean|w|
    double*   part   = (double*)(ws + 64);        // 2048 doubles
    double*   pm     = (double*)(ws + 16448);     // 2048 doubles
    unsigned* pc     = (unsigned*)(ws + 32832);   // 2048 uints
    __bf16*   xb     = (__bf16*)(ws + 65536);                                   // 64 MB
    __bf16*   tern   = (__bf16*)(ws + 65536 + (size_t)M_DIM * K_DIM * 2);       // 32 MB

    k_pre<<<10240, 256, 0, stream>>>((const float4*)w, part, (const float4*)x, (bf16x4*)xb);
    k_quant<<<2048, 256, 0, stream>>>((const float4*)w, (bf16x4*)tern, part, d_scal, pm, pc);

    dim3 grid(512);
    ternary_gemm<<<grid, 512, 0, stream>>>(xb, tern, bias, d_scal, pm, pc, out);
}